// Round 8
// baseline (71.876 us; speedup 1.0000x reference)
//
#include <hip/hip_runtime.h>

static constexpr int  D   = 64;        // embedding dim (C)
static constexpr int  KC  = 1024;      // codebook size
static constexpr int  HW  = 4096;      // 64*64
static constexpr long QSZ = 16L*64*64*64;  // elems per output tensor
static constexpr float GAPT = 0.01f;   // acc-domain gap (= d-gap 0.02); split err ~1e-3

// ---- d_ws layout (bytes) ----
static constexpr size_t WS_ENORM = 0;        // f32[1024]  sum e^2 (recheck)
static constexpr size_t WS_ENH   = 4096;     // f32[1024]  -0.5*sum e^2 (C-init)
static constexpr size_t WS_ES    = 8192;     // u16[131072] staged codebook (256 KB)
                                             //   [chunk32][hi:2048|lo:2048 u16]
                                             //   per table: [g8][col32][8]  (g = dim>>3)
static constexpr size_t WS_CNT   = 270336;   // i32 flagged-row count
static constexpr size_t WS_LIST  = 270340;   // i32[65536] flagged rows
static constexpr size_t WS_NEED  = 532484;

typedef __attribute__((ext_vector_type(8))) short s16x8;   // 8 bf16 (4 VGPR)
typedef __attribute__((ext_vector_type(4))) float f32x4;   // MFMA C/D

__device__ __forceinline__ unsigned short f2bf(float x) {  // RN-even
  union { float f; unsigned u; } v; v.f = x;
  unsigned r = v.u + 0x7FFFu + ((v.u >> 16) & 1u);
  return (unsigned short)(r >> 16);
}
__device__ __forceinline__ float bf2f(unsigned short h) {
  union { unsigned u; float f; } v; v.u = ((unsigned)h) << 16; return v.f;
}
__device__ __forceinline__ void gload_lds16(const void* g, void* l) {
  __builtin_amdgcn_global_load_lds(
      (const __attribute__((address_space(1))) void*)g,
      (__attribute__((address_space(3))) void*)l, 16, 0, 0);
}

// ---------------------------------------------------------------------------
// prep: enorm/enormh[k], bf16 hi/lo split of E into chunked staged layout
// ---------------------------------------------------------------------------
__global__ void __launch_bounds__(64) prep_kernel(const float* __restrict__ E,
                                                  float* __restrict__ enorm,
                                                  float* __restrict__ enormh,
                                                  unsigned short* __restrict__ Es,
                                                  int* __restrict__ cnt) {
  const int k = blockIdx.x, c = threadIdx.x;
  if (k == 0 && c == 0) *cnt = 0;
  const float v = E[k * D + c];
  const unsigned short hb = f2bf(v);
  const unsigned short lb = f2bf(v - bf2f(hb));
  const int chunk = k >> 5, col = k & 31, g = c >> 3, j = c & 7;
  unsigned short* base = Es + (size_t)chunk * 4096 + g * 256 + col * 8 + j;
  base[0]    = hb;
  base[2048] = lb;
  float s = v * v;
#pragma unroll
  for (int off = 32; off; off >>= 1) s += __shfl_down(s, off, 64);
  if (c == 0) { enorm[k] = s; enormh[k] = -0.5f * s; }
}

// ---------------------------------------------------------------------------
// main kernel: 512 blocks x 256 thr. Block = TWO (b,h) tiles = 128 rows.
// M-split waves: wave owns 32 rows (mi=2) x ALL 1024 cols -> each staged
// B-fragment LDS read feeds 2 MFMAs (halves LDS-pipe traffic vs R7, which
// was the measured bottleneck: ~20us/CU of ds_read issue). 2-phase LDS
// double-buffered codebook staging via global_load_lds, as proven in R7.
// ---------------------------------------------------------------------------
__global__ void __launch_bounds__(256)
vq_mfma_kernel(const float* __restrict__ X,
               const float* __restrict__ E,
               const float* __restrict__ enormh,
               const unsigned short* __restrict__ Es,
               float* __restrict__ out,
               int* __restrict__ cnt,
               int* __restrict__ list) {
  __shared__ float Xt[128][66];   // X tile, row-major; stride 66: 2-way LDS = free
  __shared__ __attribute__((aligned(16))) unsigned short Bs[2][4096];  // 2x8KB chunk
  __shared__ int idx_s[128];

  const int tid  = threadIdx.x;
  const int wave = tid >> 6;
  const int lane = tid & 63;
  const int c15  = lane & 15;
  const int kg   = lane >> 4;
  const int bh2  = blockIdx.x;        // 0..511
  const int bb   = bh2 >> 5;          // batch
  const int hbase= (bh2 & 31) * 2;    // first of two h rows

  // stage chunk 0 immediately (latency hides under phase A/B)
  {
    const unsigned short* g0 = Es + wave * 1024 + lane * 8;
#pragma unroll
    for (int is = 0; is < 2; ++is)
      gload_lds16(g0 + is * 512, &Bs[0][wave * 1024 + is * 512]);
  }

  // ---- phase A: stage 128x64 X-slice (transposed to row-major) ----
  const float* __restrict__ xbase = X + (size_t)bb * (D * HW) + hbase * 64;
  {
    const int w = tid & 63, c0 = tid >> 6;
#pragma unroll
    for (int hh = 0; hh < 2; ++hh)
#pragma unroll
      for (int i = 0; i < 16; ++i)
        Xt[hh * 64 + w][c0 + i * 4] = xbase[(c0 + i * 4) * HW + hh * 64 + w];
  }
  __syncthreads();   // Xt + Bs[0] ready (barrier drains vmcnt)

  // ---- phase B: A-fragments (bf16 hi/lo) for this wave's 32 rows ----
  s16x8 ah[2][2], al[2][2];
#pragma unroll
  for (int mi = 0; mi < 2; ++mi) {
    const int row = wave * 32 + mi * 16 + c15;
#pragma unroll
    for (int ks = 0; ks < 2; ++ks) {
      const float* xp = &Xt[row][ks * 32 + kg * 8];
      s16x8 hh, ll;
#pragma unroll
      for (int j = 0; j < 8; ++j) {
        const float x = xp[j];
        const unsigned short hb = f2bf(x);
        hh[j] = (short)hb;
        ll[j] = (short)f2bf(x - bf2f(hb));
      }
      ah[mi][ks] = hh; al[mi][ks] = ll;
    }
  }

  // ---- phase C: sweep 32 chunks of 32 cols, LDS double-buffered ----
  float b1[2][4], b2[2][4]; int i1[2][4];
#pragma unroll
  for (int mi = 0; mi < 2; ++mi)
#pragma unroll
    for (int r = 0; r < 4; ++r) { b1[mi][r] = -3.4e38f; b2[mi][r] = -3.4e38f; i1[mi][r] = 0; }

  for (int t = 0; t < 32; ++t) {
    const int cur = t & 1;
    if (t < 31) {   // stage next chunk into the other buffer
      const unsigned short* g0 = Es + (size_t)(t + 1) * 4096 + wave * 1024 + lane * 8;
#pragma unroll
      for (int is = 0; is < 2; ++is)
        gload_lds16(g0 + is * 512, &Bs[cur ^ 1][wave * 1024 + is * 512]);
    }
#pragma unroll
    for (int ni = 0; ni < 2; ++ni) {
      const int colc = ni * 16 + c15;                 // col within chunk
      const unsigned short* bp = &Bs[cur][colc * 8];  // + g*256, g = ks*4+kg
      const s16x8 fh0 = *(const s16x8*)(bp + (kg    ) * 256);
      const s16x8 fh1 = *(const s16x8*)(bp + (kg + 4) * 256);
      const s16x8 fl0 = *(const s16x8*)(bp + 2048 + (kg    ) * 256);
      const s16x8 fl1 = *(const s16x8*)(bp + 2048 + (kg + 4) * 256);
      const int col = t * 32 + colc;
      const float en = enormh[col];                   // 4KB table, L1-resident
#pragma unroll
      for (int mi = 0; mi < 2; ++mi) {
        f32x4 acc = {en, en, en, en};
        acc = __builtin_amdgcn_mfma_f32_16x16x32_bf16(ah[mi][0], fh0, acc, 0, 0, 0);
        acc = __builtin_amdgcn_mfma_f32_16x16x32_bf16(al[mi][0], fh0, acc, 0, 0, 0);
        acc = __builtin_amdgcn_mfma_f32_16x16x32_bf16(ah[mi][0], fl0, acc, 0, 0, 0);
        acc = __builtin_amdgcn_mfma_f32_16x16x32_bf16(ah[mi][1], fh1, acc, 0, 0, 0);
        acc = __builtin_amdgcn_mfma_f32_16x16x32_bf16(al[mi][1], fh1, acc, 0, 0, 0);
        acc = __builtin_amdgcn_mfma_f32_16x16x32_bf16(ah[mi][1], fl1, acc, 0, 0, 0);
#pragma unroll
        for (int r = 0; r < 4; ++r) {
          const float x  = acc[r];
          const bool  gt = x > b1[mi][r];
          b2[mi][r] = __builtin_amdgcn_fmed3f(b2[mi][r], x, b1[mi][r]);  // 2nd-best
          b1[mi][r] = gt ? x   : b1[mi][r];
          i1[mi][r] = gt ? col : i1[mi][r];
        }
      }
    }
    __syncthreads();  // stage t+1 landed; all waves done reading Bs[cur]
  }

  // ---- phase D: merge best/2nd across the 16 col-lanes (MAX semantics) ----
#pragma unroll
  for (int mi = 0; mi < 2; ++mi) {
#pragma unroll
    for (int r = 0; r < 4; ++r) {
      float B1 = b1[mi][r], B2 = b2[mi][r]; int I1 = i1[mi][r];
#pragma unroll
      for (int m = 1; m < 16; m <<= 1) {
        const float o1 = __shfl_xor(B1, m, 64);
        const float o2 = __shfl_xor(B2, m, 64);
        const int   oi = __shfl_xor(I1, m, 64);
        const float n2 = fmaxf(fmaxf(B2, o2), fminf(B1, o1));
        if (o1 > B1) { B1 = o1; I1 = oi; }
        B2 = n2;
      }
      if (c15 == 0) {
        const int rl = wave * 32 + mi * 16 + kg * 4 + r;   // row in 128-tile
        idx_s[rl] = I1;
        if (B1 - B2 < GAPT) {                    // near-tie -> exact recheck
          const int pos = atomicAdd(cnt, 1);
          list[pos] = bh2 * 128 + rl;            // linear n index
        }
      }
    }
  }
  __syncthreads();

  // ---- phase E: outputs (coalesced; eq tile overlaid onto Xt) ----
  float* __restrict__ qout = out;
  float* __restrict__ lat  = out + QSZ;
  float* __restrict__ ql   = out + 2 * QSZ;
  const size_t n0 = (size_t)bh2 * 128;

#pragma unroll
  for (int i = 0; i < 32; ++i) {
    const int e_ = i * 256 + tid;
    const int w = e_ >> 6, c = e_ & 63;        // w: row in tile 0..127
    const float q = E[idx_s[w] * D + c];       // coalesced gather (w uniform/group)
    ql[(n0 + w) * D + c]  = q;
    lat[(n0 + w) * D + c] = Xt[w][c];
    Xt[w][c] = q;                               // overlay: each slot read then written
  }
  __syncthreads();
  float* __restrict__ qb = qout + (size_t)bb * (D * HW) + hbase * 64;
#pragma unroll
  for (int i = 0; i < 32; ++i) {
    const int e_ = i * 256 + tid;
    const int c = e_ >> 7, rl = e_ & 127;      // 64 c-values x 128 rows
    qb[c * HW + rl] = Xt[rl][c];               // coalesced over rl
  }
}

// ---------------------------------------------------------------------------
// exact fp32 recheck for flagged rows (lowest-index tie-break), 1 wave/row
// ---------------------------------------------------------------------------
__global__ void __launch_bounds__(64) recheck_kernel(const float* __restrict__ X,
                                                     const float* __restrict__ E,
                                                     const float* __restrict__ enorm,
                                                     const int* __restrict__ cnt,
                                                     const int* __restrict__ list,
                                                     float* __restrict__ out) {
  __shared__ float fsh[64];
  const int lane = threadIdx.x;
  const int n = *cnt;
  for (int ii = blockIdx.x; ii < n; ii += gridDim.x) {
    const int row = list[ii];
    const int b = row >> 12, h = (row >> 6) & 63, w = row & 63;
    fsh[lane] = X[((size_t)b * D + lane) * HW + h * 64 + w];
    __syncthreads();
    float best = 3.4e38f; int bidx = 0;
    for (int j = 0; j < 16; ++j) {
      const int k = lane + j * 64;
      const float* __restrict__ e = E + k * D;
      float a0 = 0.f, a1 = 0.f, a2 = 0.f, a3 = 0.f;
#pragma unroll
      for (int c = 0; c < D; c += 4) {
        a0 = fmaf(fsh[c + 0], e[c + 0], a0);
        a1 = fmaf(fsh[c + 1], e[c + 1], a1);
        a2 = fmaf(fsh[c + 2], e[c + 2], a2);
        a3 = fmaf(fsh[c + 3], e[c + 3], a3);
      }
      const float s = enorm[k] - 2.0f * ((a0 + a1) + (a2 + a3));
      if (s < best) { best = s; bidx = k; }
    }
#pragma unroll
    for (int m = 1; m < 64; m <<= 1) {
      const float ob = __shfl_xor(best, m, 64);
      const int   oi = __shfl_xor(bidx, m, 64);
      if (ob < best || (ob == best && oi < bidx)) { best = ob; bidx = oi; }
    }
    const float q = E[bidx * D + lane];
    float* __restrict__ ql = out + 2 * QSZ;
    ql[(size_t)row * D + lane] = q;
    out[((size_t)b * D + lane) * HW + h * 64 + w] = q;
    __syncthreads();
  }
}

// ---------------------------------------------------------------------------
// fallback (R1 kernels) if ws_size is too small for the staged tables
// ---------------------------------------------------------------------------
__global__ void __launch_bounds__(64) enorm_kernel(const float* __restrict__ E,
                                                   float* __restrict__ enorm) {
  const int k = blockIdx.x, c = threadIdx.x;
  float v = E[k * D + c];
  float s = v * v;
#pragma unroll
  for (int off = 32; off; off >>= 1) s += __shfl_down(s, off, 64);
  if (c == 0) enorm[k] = s;
}

__global__ void __launch_bounds__(256) vq_kernel(const float* __restrict__ X,
                                                 const float* __restrict__ E,
                                                 const float* __restrict__ enorm,
                                                 float* __restrict__ out) {
  const int bh = blockIdx.x, b = bh >> 6, h = bh & 63;
  const int tid = threadIdx.x, wave = tid >> 6, lane = tid & 63;
  const float* __restrict__ xbase = X + (size_t)b * (D * HW) + h * 64;
  float f[D];
#pragma unroll
  for (int c = 0; c < D; ++c) f[c] = xbase[c * HW + lane];
  float best = 3.4e38f; int bidx = 0;
  const int k0 = wave * (KC / 4);
  for (int k = k0; k < k0 + (KC / 4); ++k) {
    const float* __restrict__ e = E + k * D;
    float a0 = 0.f, a1 = 0.f, a2 = 0.f, a3 = 0.f;
#pragma unroll
    for (int c = 0; c < D; c += 4) {
      a0 = fmaf(f[c + 0], e[c + 0], a0);
      a1 = fmaf(f[c + 1], e[c + 1], a1);
      a2 = fmaf(f[c + 2], e[c + 2], a2);
      a3 = fmaf(f[c + 3], e[c + 3], a3);
    }
    const float score = enorm[k] - 2.0f * ((a0 + a1) + (a2 + a3));
    if (score < best) { best = score; bidx = k; }
  }
  __shared__ float sc_s[4][64]; __shared__ int id_s[4][64];
  __shared__ int idx_s[64]; __shared__ float tile[64 * 65]; __shared__ float eq[64 * 65];
  sc_s[wave][lane] = best; id_s[wave][lane] = bidx;
  if (wave == 0) {
#pragma unroll
    for (int c = 0; c < D; ++c) tile[c * 65 + lane] = f[c];
  }
  __syncthreads();
  if (tid < 64) {
    float bs = sc_s[0][tid]; int bi = id_s[0][tid];
#pragma unroll
    for (int wv = 1; wv < 4; ++wv) {
      if (sc_s[wv][tid] < bs) { bs = sc_s[wv][tid]; bi = id_s[wv][tid]; }
    }
    idx_s[tid] = bi;
  }
  __syncthreads();
  float* __restrict__ qout = out;
  float* __restrict__ lat = out + QSZ;
  float* __restrict__ ql = out + 2 * QSZ;
  const size_t n0 = (size_t)bh * 64;
#pragma unroll
  for (int i = 0; i < 16; ++i) {
    const int e_ = i * 256 + tid, w = e_ >> 6, c = e_ & 63;
    const float q = E[idx_s[w] * D + c];
    eq[w * 65 + c] = q;
    ql[(n0 + w) * D + c] = q;
    lat[(n0 + w) * D + c] = tile[c * 65 + w];
  }
  __syncthreads();
  float* __restrict__ qb = qout + (size_t)b * (D * HW) + h * 64;
#pragma unroll
  for (int i = 0; i < 16; ++i) {
    const int e_ = i * 256 + tid, c = e_ >> 6, w = e_ & 63;
    qb[c * HW + w] = eq[w * 65 + c];
  }
}

extern "C" void kernel_launch(void* const* d_in, const int* in_sizes, int n_in,
                              void* d_out, int out_size, void* d_ws, size_t ws_size,
                              hipStream_t stream) {
  const float* X = (const float*)d_in[0];
  const float* E = (const float*)d_in[1];
  float* out = (float*)d_out;
  char* ws = (char*)d_ws;

  if (ws_size >= WS_NEED) {
    float* enorm  = (float*)(ws + WS_ENORM);
    float* enormh = (float*)(ws + WS_ENH);
    unsigned short* Es = (unsigned short*)(ws + WS_ES);
    int* cnt  = (int*)(ws + WS_CNT);
    int* list = (int*)(ws + WS_LIST);
    prep_kernel<<<KC, 64, 0, stream>>>(E, enorm, enormh, Es, cnt);
    vq_mfma_kernel<<<512, 256, 0, stream>>>(X, E, enormh, Es, out, cnt, list);
    recheck_kernel<<<512, 64, 0, stream>>>(X, E, enorm, cnt, list, out);
  } else {
    float* enorm = (float*)ws;
    enorm_kernel<<<KC, 64, 0, stream>>>(E, enorm);
    vq_kernel<<<1024, 256, 0, stream>>>(X, E, enorm, out);
  }
}